// Round 21
// baseline (52.177 us; speedup 1.0000x reference)
//
#include <hip/hip_runtime.h>
#include <hip/hip_fp16.h>

// SSIM loss — round 21: DMA-staged f32 planes + fused convert + r20 MFMA core.
// gload_lds(16B) stages a/b f32 halo planes into a PADDED layout (336B/row:
// per-lane source freedom realizes padding from linear DMA) -> h-phase reads
// 2x b128 f32 per plane, converts to f16 fragments in-register, operand-swap
// MFMA (D rows = image rows -> b64 col-major stores), v-phase windows {0,12}.
// No prep pass, no VGPR global round-trip. 512 thr, LDS 51KB -> 3 blk/CU.

#define IMGH 512
#define IMGW 512
#define TW 64
#define TH 32
#define GX 8
#define GY 16
#define GZ 48
#define NBLOCKS (GX * GY * GZ)   // 6144
#define NPIX (16 * 3 * 512 * 512)
#define C1F 1.0e-4f
#define C2F 9.0e-4f

#define SROW 84            // f32 words per staged row (80 data + 4 pad) = 336B
#define SPLANE (42 * SROW) // 3528 f32
#define SPLANE_B (SPLANE * 4)        // 14,112 B
#define STAGE_B (2 * SPLANE_B)       // 28,224 B
#define VSTRIDE 44         // halfs/col (88B); rows 42,43 zeroed (window 12)
#define VPLANE (64 * VSTRIDE)
#define WBASE 34

// Gaussian weights, sigma=1.5, ws=11 (validated r1-r20).
#define W0 0.0010283818f
#define W1 0.0075987503f
#define W2 0.0360007547f
#define W3 0.1093606960f
#define W4 0.2130055367f
#define W5 0.2660117184f

typedef _Float16 half8v __attribute__((ext_vector_type(8)));
typedef float f32x4 __attribute__((ext_vector_type(4)));
union H8 { half8v v; __half2 h2[4]; float4 f4; unsigned u[4]; };

static __device__ __forceinline__ __half2 pkrtz(float a, float b) {
    auto r = __builtin_amdgcn_cvt_pkrtz(a, b);   // __fp16 ext_vector(2)
    return *reinterpret_cast<__half2*>(&r);
}
static __device__ __forceinline__ void gload16(const void* g, void* l) {
    __builtin_amdgcn_global_load_lds(
        (const __attribute__((address_space(1))) void*)g,
        (__attribute__((address_space(3))) void*)l, 16, 0, 0);
}

__global__ __launch_bounds__(512, 6)
void ssim_tile(const float* __restrict__ img1, const float* __restrict__ img2,
               float* __restrict__ partials) {
    __shared__ float sStage[2 * SPLANE];    // 28,224 B : a-plane | b-plane
    __shared__ _Float16 sV[4 * VPLANE];     // 22,528 B : col-major, 44 rows
    __shared__ _Float16 sWext[96];
    __shared__ float wsum[8];

    const int tid  = threadIdx.x;
    const int lane = tid & 63;
    const int wv   = tid >> 6;
    const int lr = lane & 15;
    const int kc = lane >> 4;
    const int r0 = blockIdx.y * TH;
    const int c0 = blockIdx.x * TW;
    const size_t pbase = (size_t)blockIdx.z * (IMGH * IMGW);
    const float* a0 = img1 + pbase;
    const float* b0 = img2 + pbase;
    const bool fast = (blockIdx.x >= 1) & (blockIdx.x <= GX - 2) &
                      (blockIdx.y >= 1) & (blockIdx.y <= GY - 2);

    // ---- boundary blocks: pre-zero stage so skipped DMA lanes read 0 ----
    if (!fast) {
        const float4 z4 = make_float4(0.f, 0.f, 0.f, 0.f);
        for (int t = tid; t < 2 * SPLANE / 4; t += 512)
            reinterpret_cast<float4*>(sStage)[t] = z4;
        __syncthreads();
    }

    // ---- weight table + zero sV rows 42,43 ----
    if (tid < 96) {
        const float W[11] = {W0, W1, W2, W3, W4, W5, W4, W3, W2, W1, W0};
        float w = 0.f;
#pragma unroll
        for (int j = 0; j < 11; ++j) w = (tid == WBASE + j) ? W[j] : w;
        sWext[tid] = (_Float16)w;
    }
    if (tid < 256) {
        const int q = tid >> 6, col = tid & 63;
        *reinterpret_cast<unsigned*>(&sV[q * VPLANE + col * VSTRIDE + 42]) = 0u;
    }

    // ---- DMA stage: 28 issues x 1024B; per-lane source realizes padding ----
    for (int i = wv; i < 28; i += 8) {
        const int o = (i << 10) + (lane << 4);      // LDS byte offset
        if (o < STAGE_B) {
            const int plane = o >= SPLANE_B;
            const int po = o - plane * SPLANE_B;
            const int row = (unsigned)po / 336u;
            const int c4 = (po - row * 336) >> 4;   // 16B chunk in row, 0..20
            if (c4 < 20) {                          // 20 = pad chunk: skip
                const int gr = r0 - 5 + row;
                const int gc = c0 - 8 + (c4 << 2);
                if (fast || ((unsigned)gr < IMGH && (unsigned)gc < IMGW)) {
                    const float* g = (plane ? b0 : a0) + (size_t)gr * IMGW + gc;
                    gload16(g, reinterpret_cast<char*>(sStage) + (i << 10));
                }
            }
        }
    }
    __syncthreads();

    // ---- weight fragments (m89 layout: M/N=lane&15, K=(lane>>4)*8+e) ----
    half8v Wh, Av0, Av1;
    {
        const int bi = (kc << 3) - lr + WBASE;
#pragma unroll
        for (int e = 0; e < 8; ++e) Wh[e]  = sWext[bi - 3 + e];   // W[k-n-3]
#pragma unroll
        for (int e = 0; e < 8; ++e) Av0[e] = sWext[bi + e];       // W[k-m]
#pragma unroll
        for (int e = 0; e < 8; ++e) Av1[e] = sWext[bi - 4 + e];   // W[k-m-4]
    }

    // ---- h-phase: 24 half-positions (rt,ct,qp), 3/wave; convert fused ----
    {
        const int ct = (wv >> 1) & 3;
        const int qp = wv & 1;
#pragma unroll
        for (int rt = 0; rt < 3; ++rt) {
            const int rb = (rt == 0) ? 0 : (rt == 1 ? 16 : 26);
            const int fo = (rb + lr) * SROW + 16 * ct + (kc << 3); // f32 idx
            float4 va1 = *reinterpret_cast<const float4*>(&sStage[fo]);
            float4 va2 = *reinterpret_cast<const float4*>(&sStage[fo + 4]);
            float4 vb1 = *reinterpret_cast<const float4*>(&sStage[SPLANE + fo]);
            float4 vb2 = *reinterpret_cast<const float4*>(&sStage[SPLANE + fo + 4]);
            H8 ha, hb;
            ha.h2[0] = pkrtz(va1.x, va1.y); ha.h2[1] = pkrtz(va1.z, va1.w);
            ha.h2[2] = pkrtz(va2.x, va2.y); ha.h2[3] = pkrtz(va2.z, va2.w);
            hb.h2[0] = pkrtz(vb1.x, vb1.y); hb.h2[1] = pkrtz(vb1.z, vb1.w);
            hb.h2[2] = pkrtz(vb2.x, vb2.y); hb.h2[3] = pkrtz(vb2.z, vb2.w);
            H8 f0, f1;
            if (qp == 0) {
                f0 = ha; f1 = hb;
            } else {
#pragma unroll
                for (int t = 0; t < 4; ++t) {
                    f0.h2[t] = __hfma2(ha.h2[t], ha.h2[t],
                                       __hmul2(hb.h2[t], hb.h2[t]));
                    f1.h2[t] = __hmul2(ha.h2[t], hb.h2[t]);
                }
            }
            f32x4 d0 = {0.f, 0.f, 0.f, 0.f}, d1 = d0;
            d0 = __builtin_amdgcn_mfma_f32_16x16x32_f16(f0.v, Wh, d0, 0, 0, 0);
            d1 = __builtin_amdgcn_mfma_f32_16x16x32_f16(f1.v, Wh, d1, 0, 0, 0);
            const int p0 = qp * 2, p1 = qp * 2 + 1;
            const int vb = (16 * ct + lr) * VSTRIDE + rb + (kc << 2);
            uint2 s0, s1;
            __half2 h;
            h = pkrtz(d0[0], d0[1]); s0.x = *reinterpret_cast<unsigned*>(&h);
            h = pkrtz(d0[2], d0[3]); s0.y = *reinterpret_cast<unsigned*>(&h);
            h = pkrtz(d1[0], d1[1]); s1.x = *reinterpret_cast<unsigned*>(&h);
            h = pkrtz(d1[2], d1[3]); s1.y = *reinterpret_cast<unsigned*>(&h);
            if (rt < 2) {
                *reinterpret_cast<uint2*>(&sV[p0 * VPLANE + vb]) = s0;
                *reinterpret_cast<uint2*>(&sV[p1 * VPLANE + vb]) = s1;
            } else {     // rb=26: 4B-aligned only
                unsigned* q0 = reinterpret_cast<unsigned*>(&sV[p0 * VPLANE + vb]);
                unsigned* q1 = reinterpret_cast<unsigned*>(&sV[p1 * VPLANE + vb]);
                q0[0] = s0.x; q0[1] = s0.y;
                q1[0] = s1.x; q1[1] = s1.y;
            }
        }
    }
    __syncthreads();

    // ---- v-phase: wave wv: ct2 = wv&3, rt2 = wv>>2; 2xb64 reads ----
    float lsum = 0.f;
    {
        const int ct2 = wv & 3;
        const int rt2 = wv >> 2;
        const int w0 = rt2 ? 12 : 0;
        const half8v Avx = rt2 ? Av1 : Av0;
        const int vbase = (16 * ct2 + lr) * VSTRIDE + w0 + (kc << 3);
        auto vread = [&](int q) -> half8v {
            const _Float16* p = &sV[q * VPLANE + vbase];
            H8 c;
            *reinterpret_cast<uint2*>(&c.u[0]) =
                *reinterpret_cast<const uint2*>(p);
            *reinterpret_cast<uint2*>(&c.u[2]) =
                *reinterpret_cast<const uint2*>(p + 4);
            return c.v;
        };
        f32x4 d0 = {0.f, 0.f, 0.f, 0.f}, d1 = d0, d2 = d0, d3 = d0;
        d0 = __builtin_amdgcn_mfma_f32_16x16x32_f16(Avx, vread(0), d0, 0, 0, 0);
        d1 = __builtin_amdgcn_mfma_f32_16x16x32_f16(Avx, vread(1), d1, 0, 0, 0);
        d2 = __builtin_amdgcn_mfma_f32_16x16x32_f16(Avx, vread(2), d2, 0, 0, 0);
        d3 = __builtin_amdgcn_mfma_f32_16x16x32_f16(Avx, vread(3), d3, 0, 0, 0);
#pragma unroll
        for (int r = 0; r < 4; ++r) {
            const float mu1 = d0[r], mu2 = d1[r], S = d2[r], eab = d3[r];
            const float mu11 = mu1 * mu1, mu22 = mu2 * mu2, mu12 = mu1 * mu2;
            const float s12 = eab - mu12;
            const float num = (2.f * mu12 + C1F) * (2.f * s12 + C2F);
            const float den = (mu11 + mu22 + C1F) * ((S - mu11 - mu22) + C2F);
            lsum += num * __builtin_amdgcn_rcpf(den);
        }
    }

    // ---- deterministic block reduction (8 waves) ----
#pragma unroll
    for (int off = 32; off > 0; off >>= 1) lsum += __shfl_down(lsum, off, 64);
    if (lane == 0) wsum[wv] = lsum;
    __syncthreads();
    if (tid == 0) {
        float t = 0.f;
#pragma unroll
        for (int w = 0; w < 8; ++w) t += wsum[w];
        partials[((size_t)blockIdx.z * GY + blockIdx.y) * GX + blockIdx.x] = t;
    }
}

__global__ __launch_bounds__(1024)
void ssim_reduce(const float* __restrict__ partials, float* __restrict__ out, int n) {
    __shared__ float lds[1024];
    float s = 0.f;
    for (int i = threadIdx.x; i < n; i += 1024) s += partials[i];
    lds[threadIdx.x] = s;
    __syncthreads();
    for (int off = 512; off > 0; off >>= 1) {
        if ((int)threadIdx.x < off) lds[threadIdx.x] += lds[threadIdx.x + off];
        __syncthreads();
    }
    if (threadIdx.x == 0) out[0] = 1.f - lds[0] / (float)NPIX;
}

extern "C" void kernel_launch(void* const* d_in, const int* in_sizes, int n_in,
                              void* d_out, int out_size, void* d_ws, size_t ws_size,
                              hipStream_t stream) {
    const float* img1 = (const float*)d_in[0];
    const float* img2 = (const float*)d_in[1];
    float* out = (float*)d_out;
    float* partials = (float*)d_ws;

    dim3 grid(GX, GY, GZ);
    ssim_tile<<<grid, 512, 0, stream>>>(img1, img2, partials);
    ssim_reduce<<<1, 1024, 0, stream>>>(partials, out, NBLOCKS);
}

// Round 22
// 39.929 us; speedup vs baseline: 1.3067x; 1.3067x over previous
//
#include <hip/hip_runtime.h>
#include <hip/hip_fp16.h>

// SSIM loss — round 22: r20 + inline-asm batched prep loads.
// The compiler's register-miser (VGPR=16) serialized prep's 4 global loads
// (4x ~400cy exposed latency, barrier-correlated). An asm blob of 4
// global_load_dwordx4 + one s_waitcnt vmcnt(0) forces parallel issue.
// Aux work (weight table, sV row-42/43 zeroing) moved to wave 7 (idle in
// prep). Rest identical to r20: operand-swapped h-MFMA (D rows = image rows
// -> b64 col-major stores), q-pair split, v windows {0,12}, 2xb64 v-reads.
// 512 thr, LDS 37.9KB -> 4 blocks/CU.

#define IMGH 512
#define IMGW 512
#define TW 64
#define TH 32
#define GX 8
#define GY 16
#define GZ 48
#define NBLOCKS (GX * GY * GZ)   // 6144
#define NPIX (16 * 3 * 512 * 512)
#define C1F 1.0e-4f
#define C2F 9.0e-4f

#define INSTRIDE 88        // halfs/row (176B, b128-aligned reads)
#define INPLANE (42 * INSTRIDE)
#define VSTRIDE 44         // halfs/col (88B); rows 42,43 zeroed for window 12
#define VPLANE (64 * VSTRIDE)
#define WBASE 34

// Gaussian weights, sigma=1.5, ws=11 (validated r1-r21).
#define W0 0.0010283818f
#define W1 0.0075987503f
#define W2 0.0360007547f
#define W3 0.1093606960f
#define W4 0.2130055367f
#define W5 0.2660117184f

typedef _Float16 half8v __attribute__((ext_vector_type(8)));
typedef float f32x4 __attribute__((ext_vector_type(4)));
union H8 { half8v v; __half2 h2[4]; float4 f4; unsigned u[4]; };

static __device__ __forceinline__ __half2 pkrtz(float a, float b) {
    auto r = __builtin_amdgcn_cvt_pkrtz(a, b);   // __fp16 ext_vector(2)
    return *reinterpret_cast<__half2*>(&r);
}
static __device__ __forceinline__ float wval(int i) {
    const float W[11] = {W0, W1, W2, W3, W4, W5, W4, W3, W2, W1, W0};
    float w = 0.f;
#pragma unroll
    for (int j = 0; j < 11; ++j) w = (i == WBASE + j) ? W[j] : w;
    return w;
}

__global__ __launch_bounds__(512, 8)
void ssim_tile(const float* __restrict__ img1, const float* __restrict__ img2,
               float* __restrict__ partials) {
    __shared__ _Float16 sWext[96];          // [WBASE..WBASE+10] = W[0..10]
    __shared__ _Float16 sIn[2 * INPLANE];   // 14,784 B : a | b
    __shared__ _Float16 sV[4 * VPLANE];     // 22,528 B : col-major, 44 rows
    __shared__ float wsum[8];

    const int tid  = threadIdx.x;
    const int lane = tid & 63;
    const int wv   = tid >> 6;
    const int lr = lane & 15;
    const int kc = lane >> 4;
    const int r0 = blockIdx.y * TH;
    const int c0 = blockIdx.x * TW;
    const size_t pbase = (size_t)blockIdx.z * (IMGH * IMGW);
    const float* a0 = img1 + pbase;
    const float* b0 = img2 + pbase;
    const bool fast = (blockIdx.x >= 1) & (blockIdx.x <= GX - 2) &
                      (blockIdx.y >= 1) & (blockIdx.y <= GY - 2);

    // ---- prep (waves 0-6) ∥ aux work (wave 7) ----
    if (tid < 420) {
        const int row = (unsigned)tid / 10u;
        const int ch  = tid - row * 10;
        const int gr = r0 - 5 + row;
        const int gc = c0 - 8 + 8 * ch;
        f32x4 va1, va2, vb1, vb2;
        if (fast) {
            const float* pa = a0 + (size_t)gr * IMGW + gc;
            const float* pb = b0 + (size_t)gr * IMGW + gc;
            // one blob: 4 loads in flight, single latency exposure
            asm volatile(
                "global_load_dwordx4 %0, %4, off\n\t"
                "global_load_dwordx4 %1, %4, off offset:16\n\t"
                "global_load_dwordx4 %2, %5, off\n\t"
                "global_load_dwordx4 %3, %5, off offset:16\n\t"
                "s_waitcnt vmcnt(0)"
                : "=&v"(va1), "=&v"(va2), "=&v"(vb1), "=&v"(vb2)
                : "v"(pa), "v"(pb)
                : "memory");
        } else {
            va1 = (f32x4){0.f, 0.f, 0.f, 0.f};
            va2 = vb1 = vb2 = va1;
            if ((unsigned)gr < IMGH && (unsigned)gc < IMGW) {
                const float* pa = a0 + (size_t)gr * IMGW + gc;
                const float* pb = b0 + (size_t)gr * IMGW + gc;
                va1 = *reinterpret_cast<const f32x4*>(pa);
                va2 = *reinterpret_cast<const f32x4*>(pa + 4);
                vb1 = *reinterpret_cast<const f32x4*>(pb);
                vb2 = *reinterpret_cast<const f32x4*>(pb + 4);
            }
        }
        const int off = row * INSTRIDE + 8 * ch;
        H8 ha, hb;
        ha.h2[0] = pkrtz(va1[0], va1[1]); ha.h2[1] = pkrtz(va1[2], va1[3]);
        ha.h2[2] = pkrtz(va2[0], va2[1]); ha.h2[3] = pkrtz(va2[2], va2[3]);
        hb.h2[0] = pkrtz(vb1[0], vb1[1]); hb.h2[1] = pkrtz(vb1[2], vb1[3]);
        hb.h2[2] = pkrtz(vb2[0], vb2[1]); hb.h2[3] = pkrtz(vb2[2], vb2[3]);
        *reinterpret_cast<float4*>(&sIn[off]) = ha.f4;
        *reinterpret_cast<float4*>(&sIn[INPLANE + off]) = hb.f4;
    } else if (tid >= 448) {
        const int t = tid - 448;               // 0..63
        sWext[t] = (_Float16)wval(t);
        if (t < 32) sWext[t + 64] = (_Float16)wval(t + 64);
#pragma unroll
        for (int j = 0; j < 4; ++j) {          // zero sV rows 42,43 (256 words)
            const int w = t + (j << 6);
            const int q = w >> 6, col = w & 63;
            *reinterpret_cast<unsigned*>(&sV[q * VPLANE + col * VSTRIDE + 42]) = 0u;
        }
    }
    __syncthreads();

    // ---- weight fragments (m89 layout: M/N=lane&15, K=(lane>>4)*8+e) ----
    half8v Wh, Av0, Av1;
    {
        const int bi = (kc << 3) - lr + WBASE;
#pragma unroll
        for (int e = 0; e < 8; ++e) Wh[e]  = sWext[bi - 3 + e];   // W[k-n-3]
#pragma unroll
        for (int e = 0; e < 8; ++e) Av0[e] = sWext[bi + e];       // W[k-m]
#pragma unroll
        for (int e = 0; e < 8; ++e) Av1[e] = sWext[bi - 4 + e];   // W[k-m-4]
    }

    // ---- h-phase: 24 half-positions (rt,ct,qp), 3 per wave ----
    {
        const int ct = (wv >> 1) & 3;
        const int qp = wv & 1;
#pragma unroll
        for (int rt = 0; rt < 3; ++rt) {
            const int rb = (rt == 0) ? 0 : (rt == 1 ? 16 : 26);
            const int base = (rb + lr) * INSTRIDE + 16 * ct + (kc << 3);
            H8 fa, fb;
            fa.f4 = *reinterpret_cast<const float4*>(&sIn[base]);
            fb.f4 = *reinterpret_cast<const float4*>(&sIn[INPLANE + base]);
            H8 f0, f1;
            if (qp == 0) {
                f0 = fa; f1 = fb;
            } else {
#pragma unroll
                for (int t = 0; t < 4; ++t) {
                    f0.h2[t] = __hfma2(fa.h2[t], fa.h2[t],
                                       __hmul2(fb.h2[t], fb.h2[t]));
                    f1.h2[t] = __hmul2(fa.h2[t], fb.h2[t]);
                }
            }
            f32x4 d0 = {0.f, 0.f, 0.f, 0.f}, d1 = d0;
            d0 = __builtin_amdgcn_mfma_f32_16x16x32_f16(f0.v, Wh, d0, 0, 0, 0);
            d1 = __builtin_amdgcn_mfma_f32_16x16x32_f16(f1.v, Wh, d1, 0, 0, 0);
            const int p0 = qp * 2, p1 = qp * 2 + 1;
            const int vb = (16 * ct + lr) * VSTRIDE + rb + (kc << 2);
            uint2 s0, s1;
            __half2 h;
            h = pkrtz(d0[0], d0[1]); s0.x = *reinterpret_cast<unsigned*>(&h);
            h = pkrtz(d0[2], d0[3]); s0.y = *reinterpret_cast<unsigned*>(&h);
            h = pkrtz(d1[0], d1[1]); s1.x = *reinterpret_cast<unsigned*>(&h);
            h = pkrtz(d1[2], d1[3]); s1.y = *reinterpret_cast<unsigned*>(&h);
            if (rt < 2) {
                *reinterpret_cast<uint2*>(&sV[p0 * VPLANE + vb]) = s0;
                *reinterpret_cast<uint2*>(&sV[p1 * VPLANE + vb]) = s1;
            } else {     // rb=26: 4B-aligned only
                unsigned* q0 = reinterpret_cast<unsigned*>(&sV[p0 * VPLANE + vb]);
                unsigned* q1 = reinterpret_cast<unsigned*>(&sV[p1 * VPLANE + vb]);
                q0[0] = s0.x; q0[1] = s0.y;
                q1[0] = s1.x; q1[1] = s1.y;
            }
        }
    }
    __syncthreads();

    // ---- v-phase: wave wv: ct2 = wv&3, rt2 = wv>>2; 2xb64 reads ----
    float lsum = 0.f;
    {
        const int ct2 = wv & 3;
        const int rt2 = wv >> 2;
        const int w0 = rt2 ? 12 : 0;
        const half8v Avx = rt2 ? Av1 : Av0;
        const int vbase = (16 * ct2 + lr) * VSTRIDE + w0 + (kc << 3);
        auto vread = [&](int q) -> half8v {
            const _Float16* p = &sV[q * VPLANE + vbase];
            H8 c;
            *reinterpret_cast<uint2*>(&c.u[0]) =
                *reinterpret_cast<const uint2*>(p);
            *reinterpret_cast<uint2*>(&c.u[2]) =
                *reinterpret_cast<const uint2*>(p + 4);
            return c.v;
        };
        f32x4 d0 = {0.f, 0.f, 0.f, 0.f}, d1 = d0, d2 = d0, d3 = d0;
        d0 = __builtin_amdgcn_mfma_f32_16x16x32_f16(Avx, vread(0), d0, 0, 0, 0);
        d1 = __builtin_amdgcn_mfma_f32_16x16x32_f16(Avx, vread(1), d1, 0, 0, 0);
        d2 = __builtin_amdgcn_mfma_f32_16x16x32_f16(Avx, vread(2), d2, 0, 0, 0);
        d3 = __builtin_amdgcn_mfma_f32_16x16x32_f16(Avx, vread(3), d3, 0, 0, 0);
#pragma unroll
        for (int r = 0; r < 4; ++r) {
            const float mu1 = d0[r], mu2 = d1[r], S = d2[r], eab = d3[r];
            const float mu11 = mu1 * mu1, mu22 = mu2 * mu2, mu12 = mu1 * mu2;
            const float s12 = eab - mu12;
            const float num = (2.f * mu12 + C1F) * (2.f * s12 + C2F);
            const float den = (mu11 + mu22 + C1F) * ((S - mu11 - mu22) + C2F);
            lsum += num * __builtin_amdgcn_rcpf(den);
        }
    }

    // ---- deterministic block reduction (8 waves) ----
#pragma unroll
    for (int off = 32; off > 0; off >>= 1) lsum += __shfl_down(lsum, off, 64);
    if (lane == 0) wsum[wv] = lsum;
    __syncthreads();
    if (tid == 0) {
        float t = 0.f;
#pragma unroll
        for (int w = 0; w < 8; ++w) t += wsum[w];
        partials[((size_t)blockIdx.z * GY + blockIdx.y) * GX + blockIdx.x] = t;
    }
}

__global__ __launch_bounds__(1024)
void ssim_reduce(const float* __restrict__ partials, float* __restrict__ out, int n) {
    __shared__ float lds[1024];
    float s = 0.f;
    for (int i = threadIdx.x; i < n; i += 1024) s += partials[i];
    lds[threadIdx.x] = s;
    __syncthreads();
    for (int off = 512; off > 0; off >>= 1) {
        if ((int)threadIdx.x < off) lds[threadIdx.x] += lds[threadIdx.x + off];
        __syncthreads();
    }
    if (threadIdx.x == 0) out[0] = 1.f - lds[0] / (float)NPIX;
}

extern "C" void kernel_launch(void* const* d_in, const int* in_sizes, int n_in,
                              void* d_out, int out_size, void* d_ws, size_t ws_size,
                              hipStream_t stream) {
    const float* img1 = (const float*)d_in[0];
    const float* img2 = (const float*)d_in[1];
    float* out = (float*)d_out;
    float* partials = (float*)d_ws;

    dim3 grid(GX, GY, GZ);
    ssim_tile<<<grid, 512, 0, stream>>>(img1, img2, partials);
    ssim_reduce<<<1, 1024, 0, stream>>>(partials, out, NBLOCKS);
}